// Round 11
// baseline (163.893 us; speedup 1.0000x reference)
//
#include <hip/hip_runtime.h>
#include <hip/hip_bf16.h>

// B=2, S=2048, D_MODEL=1024, H=16, D_HEAD=64. I/O: float32 (per reference).
// Internal intermediates bf16. Pipeline:
//   Wt = bf16(transpose(W)) x4; qb16/kvb16 = bf16(q/kv)
//   qm = bf16((qb16@Wq+bq)*log2e/8), km = bf16(kvb16@Wk+bk), vt = (kvb16@Wv+bv)^T per head
//   attn = flash-attention(qm,km,vt) merged heads [4096,1024] bf16   (aliases qb16)
//   om = bf16(attn@Wo+bo)                                            (aliases kvb16)
//   out = f32 LayerNorm(q+om)*gamma+beta
// Attn: no online max; 512 blocks x 2 waves, G=4 q-groups/wave -> 4 blocks/CU
// (8 waves/CU = 2/SIMD for TLP) with G=4's halved LDS-read volume.
// GEMM: BK=32 2-buffer minimum-2-phase (stage-next after the single barrier).

#define DM 1024
#define SEQ 2048
#define NB 2
#define NH 16
#define DH 64

typedef __attribute__((ext_vector_type(8))) short bf16x8;
typedef __attribute__((ext_vector_type(4))) float f32x4;
typedef __attribute__((ext_vector_type(4))) unsigned int u32x4;

__device__ __forceinline__ float bf2f(short s) {
  unsigned u = ((unsigned)(unsigned short)s) << 16;
  return __builtin_bit_cast(float, u);
}
__device__ __forceinline__ short f2bf(float f) {
  unsigned u = __builtin_bit_cast(unsigned, f);
  u += 0x7fffu + ((u >> 16) & 1u);  // RNE
  return (short)(u >> 16);
}
__device__ __forceinline__ unsigned cvt_pk_bf16(float lo, float hi) {
  unsigned r;
  asm("v_cvt_pk_bf16_f32 %0, %1, %2" : "=v"(r) : "v"(lo), "v"(hi));
  return r;
}
__device__ __forceinline__ float exp2_fast(float x) {
  float r;
  asm("v_exp_f32 %0, %1" : "=v"(r) : "v"(x));
  return r;
}

#define GLL16(gsrc, ldst)                                                     \
  __builtin_amdgcn_global_load_lds(                                           \
      (const __attribute__((address_space(1))) void*)(gsrc),                  \
      (__attribute__((address_space(3))) void*)(ldst), 16, 0, 0)

// ---------------------------------------------------------------- transpose
__global__ __launch_bounds__(256) void k_transpose(
    const float* __restrict__ Wq, const float* __restrict__ Wk,
    const float* __restrict__ Wv, const float* __restrict__ Wo,
    short* __restrict__ Wt_all) {
  const int z = blockIdx.z;
  const float* src = (z == 0) ? Wq : (z == 1) ? Wk : (z == 2) ? Wv : Wo;
  short* dst = Wt_all + (size_t)z * (DM * DM);
  __shared__ float t[32][33];
  const int n0 = blockIdx.x * 32, k0 = blockIdx.y * 32;
  const int tx = threadIdx.x, ty = threadIdx.y;  // (32,8)
#pragma unroll
  for (int i = 0; i < 32; i += 8)
    t[ty + i][tx] = src[(size_t)(k0 + ty + i) * DM + n0 + tx];
  __syncthreads();
#pragma unroll
  for (int i = 0; i < 32; i += 8)
    dst[(size_t)(n0 + ty + i) * DM + k0 + tx] = f2bf(t[tx][ty + i]);
}

// ---------------------------------------------------------------- f32->bf16
__global__ __launch_bounds__(256) void k_cvt(const float* __restrict__ q,
                                             const float* __restrict__ kv,
                                             short* __restrict__ qb,
                                             short* __restrict__ kvb) {
  const int i = blockIdx.x * 256 + threadIdx.x;
  const int half = 524288;
  const float* src = (i < half) ? q : kv;
  short* dst = (i < half) ? qb : kvb;
  const size_t j = (size_t)((i < half) ? i : i - half) * 8;
  const float4 a = *(const float4*)(src + j);
  const float4 b = *(const float4*)(src + j + 4);
  u32x4 pw;
  pw[0] = cvt_pk_bf16(a.x, a.y);
  pw[1] = cvt_pk_bf16(a.z, a.w);
  pw[2] = cvt_pk_bf16(b.x, b.y);
  pw[3] = cvt_pk_bf16(b.z, b.w);
  *(bf16x8*)(dst + j) = __builtin_bit_cast(bf16x8, pw);
}

// ---------------------------------------------------------------- GEMM body
// C[m,n] = (sum_k A[m,k]*Wt[n,k] + bias[n]) * cscale; M=4096, N=K=1024.
// 128x128 tile, BK=32, 4 waves, 4x4 frags of 16x16x32. 2-phase: 2-buffer LDS
// (32KB), ONE __syncthreads per K-step, stage-next issued after the barrier
// so load latency hides under the 16 MFMAs. Source slot XOR-swizzled by
// row&3 (both-sides: reads use g^(qi&3)).
__device__ __forceinline__ void gemm_body32(short (*As)[4096], short (*Bs)[4096],
                                            const short* __restrict__ X,
                                            const short* __restrict__ Wt,
                                            const float* __restrict__ bias,
                                            short* __restrict__ out,
                                            int vt_mode, float cscale,
                                            int bx, int by) {
  const int tid = threadIdx.x;
  const int w = tid >> 6, l = tid & 63;
  const int g = l >> 4, qi = l & 15;
  const int n0 = bx * 128;
  const int m0 = by * 128;
  const int wr = w >> 1, wc = w & 1;

  f32x4 acc[4][4];
#pragma unroll
  for (int m = 0; m < 4; m++)
#pragma unroll
    for (int n = 0; n < 4; n++) acc[m][n] = (f32x4){0.f, 0.f, 0.f, 0.f};

  // staging: round jj covers rows jj*64 + w*16 + (l>>2); slot (l&3)^(row&3)
  const int srow = w * 16 + (l >> 2);
  const int scol = ((l & 3) ^ ((l >> 2) & 3)) * 8;
  const short* Ag = X + (size_t)(m0 + srow) * DM + scol;
  const short* Bg = Wt + (size_t)(n0 + srow) * DM + scol;

  auto stage = [&](int buf, int k0) {
#pragma unroll
    for (int jj = 0; jj < 2; ++jj) {
      GLL16(Ag + (size_t)(jj * 64) * DM + k0, &As[buf][jj * 2048 + w * 512]);
      GLL16(Bg + (size_t)(jj * 64) * DM + k0, &Bs[buf][jj * 2048 + w * 512]);
    }
  };

  auto compute = [&](int buf) {
    bf16x8 a[4], b[4];
    const int xo = (g ^ (qi & 3)) * 8;
#pragma unroll
    for (int m = 0; m < 4; m++)
      a[m] = *(const bf16x8*)&As[buf][(wr * 64 + m * 16 + qi) * 32 + xo];
#pragma unroll
    for (int n = 0; n < 4; n++)
      b[n] = *(const bf16x8*)&Bs[buf][(wc * 64 + n * 16 + qi) * 32 + xo];
    __builtin_amdgcn_s_setprio(1);
#pragma unroll
    for (int m = 0; m < 4; m++)
#pragma unroll
      for (int n = 0; n < 4; n++)
        acc[m][n] = __builtin_amdgcn_mfma_f32_16x16x32_bf16(a[m], b[n],
                                                            acc[m][n], 0, 0, 0);
    __builtin_amdgcn_s_setprio(0);
  };

  stage(0, 0);
  for (int ks = 0; ks < 32; ++ks) {
    __syncthreads();  // drains stage(ks) [vmcnt0] + prev buf reads [lgkm]
    if (ks < 31) stage((ks + 1) & 1, (ks + 1) * 32);
    compute(ks & 1);
  }

  const int col0 = n0 + wc * 64;
  const int row0 = m0 + wr * 64;
  float bfv[4];
#pragma unroll
  for (int n = 0; n < 4; n++) bfv[n] = bias[col0 + n * 16 + qi];

  if (!vt_mode) {
#pragma unroll
    for (int m = 0; m < 4; m++) {
#pragma unroll
      for (int n = 0; n < 4; n++) {
        const int col = col0 + n * 16 + qi;
#pragma unroll
        for (int r = 0; r < 4; r++) {
          const int row = row0 + m * 16 + g * 4 + r;
          out[(size_t)row * DM + col] = f2bf((acc[m][n][r] + bfv[n]) * cscale);
        }
      }
    }
  } else {
    // V transposed per head: out[((b*NH+h)*DH+d)*SEQ + s]
#pragma unroll
    for (int m = 0; m < 4; m++) {
      const int s_base = row0 + m * 16 + g * 4;
      const int bb = s_base >> 11;
      const int s = s_base & (SEQ - 1);
#pragma unroll
      for (int n = 0; n < 4; n++) {
        const int col = col0 + n * 16 + qi;
        const int h = col >> 6, d = col & 63;
        ushort4 v;
        v.x = (unsigned short)f2bf(acc[m][n][0] + bfv[n]);
        v.y = (unsigned short)f2bf(acc[m][n][1] + bfv[n]);
        v.z = (unsigned short)f2bf(acc[m][n][2] + bfv[n]);
        v.w = (unsigned short)f2bf(acc[m][n][3] + bfv[n]);
        *(ushort4*)&out[(((size_t)bb * NH + h) * DH + d) * SEQ + s] = v;
      }
    }
  }
}

// XCD-chunked remap of the (8 x-blocks, 32 y-blocks) grid.
__device__ __forceinline__ void xcd_remap(int& bx, int& by) {
  const int lin2 = blockIdx.x + 8 * blockIdx.y;
  const int xcd = lin2 & 7, jj = lin2 >> 3;
  bx = jj & 7;
  by = xcd * 4 + (jj >> 3);
}

__global__ __launch_bounds__(256) void k_gemm_qkv(
    const short* __restrict__ qb, const short* __restrict__ kvb,
    const short* __restrict__ Wt, const float* __restrict__ bq,
    const float* __restrict__ bk, const float* __restrict__ bv,
    short* __restrict__ qm, short* __restrict__ km, short* __restrict__ vtb) {
  __shared__ short As[2][4096], Bs[2][4096];
  const int z = blockIdx.z;
  const short* X = (z == 0) ? qb : kvb;
  const short* W = Wt + (size_t)z * (DM * DM);
  const float* bias = (z == 0) ? bq : (z == 1) ? bk : bv;
  short* out = (z == 0) ? qm : (z == 1) ? km : vtb;
  const float cs = (z == 0) ? 0.18033688011112042f : 1.0f;  // log2e/8
  int bx, by;
  xcd_remap(bx, by);
  gemm_body32(As, Bs, X, W, bias, out, z == 2, cs, bx, by);
}

__global__ __launch_bounds__(256) void k_gemm_o(
    const short* __restrict__ attn, const short* __restrict__ Wto,
    const float* __restrict__ bo, short* __restrict__ om) {
  __shared__ short As[2][4096], Bs[2][4096];
  int bx, by;
  xcd_remap(bx, by);
  gemm_body32(As, Bs, attn, Wto, bo, om, 0, 1.0f, bx, by);
}

// ---------------------------------------------------------------- attention
// Block = 2 waves x 64 q-rows (G=4 q-groups sharing K/V LDS reads) = 128
// q-rows of one (b,h); 512 blocks -> 4 blocks/CU (8 waves/CU, 2/SIMD).
// K [64key x 64dim] + V^T [64dim x 64key] per tile, 2-buffer __syncthreads
// dbuf (stage-next after barrier). No-max softmax (bounded scores).
__global__ __launch_bounds__(128) void k_attn(const short* __restrict__ qm,
                                              const short* __restrict__ km,
                                              const short* __restrict__ vt,
                                              short* __restrict__ attn) {
  __shared__ short lds[2][8192];  // per buf: K [0..4095], V^T [4096..8191]

  // XCD-chunked: xcd = lin&7 gets 4 whole (b,h) pairs -> K/V L2-resident.
  const int lin = blockIdx.x;
  const int xcd = lin & 7, j = lin >> 3;   // j 0..63
  const int pair = xcd + 8 * (j >> 4);     // 4 pairs per xcd
  const int qb = j & 15;
  const int h = pair & 15, bb = pair >> 4;
  const int q0 = qb * 128;

  const int tid = threadIdx.x;             // 0..127
  const int w = tid >> 6, l = tid & 63;    // w 0..1
  const int g = l >> 4, qi = l & 15;

  const size_t bbS = (size_t)bb * SEQ;
  const size_t vbase = ((size_t)(bb * NH + h)) * DH * SEQ;
  const short* __restrict__ kmh = km + bbS * DM + h * DH;

  // staging lane constants: skey = tid>>3 (0..15; +16j rounds), slot tid&7.
  // Swizzle keys are 16-row periodic -> j-independent (verified R5 formulas).
  const int skey = tid >> 3;
  const int sslot = tid & 7;
  const int kgq = sslot ^ ((skey >> 1) & 7);  // K dim-block at this slot
  const int vkb = sslot ^ (skey & 7);         // V key-block at this slot
  const short* __restrict__ srcK0 = kmh + (size_t)skey * DM + kgq * 8;
  const short* __restrict__ srcV0 = vt + vbase + (size_t)skey * SEQ + vkb * 8;

#define STAGE(buf, kk0)                                                       \
  {                                                                           \
    _Pragma("unroll") for (int jj = 0; jj < 4; ++jj)                          \
        GLL16(srcK0 + (size_t)((kk0) + 16 * jj) * DM,                         \
              &lds[buf][jj * 1024 + w * 512]);                                \
    _Pragma("unroll") for (int jj = 0; jj < 4; ++jj)                          \
        GLL16(srcV0 + (kk0) + (size_t)(16 * jj) * SEQ,                        \
              &lds[buf][4096 + jj * 1024 + w * 512]);                         \
  }

  // Q fragments: 4 q-groups at rows rowA + {0,16,32,48}, pre-scaled log2e/8
  const int rowA = q0 + w * 64 + qi;
  const short* Qp = qm + (bbS + rowA) * DM + h * DH;
  const bf16x8 qA0 = *(const bf16x8*)(Qp + 8 * g);
  const bf16x8 qA1 = *(const bf16x8*)(Qp + 32 + 8 * g);
  const bf16x8 qB0 = *(const bf16x8*)(Qp + 16 * DM + 8 * g);
  const bf16x8 qB1 = *(const bf16x8*)(Qp + 16 * DM + 32 + 8 * g);
  const bf16x8 qC0 = *(const bf16x8*)(Qp + 32 * DM + 8 * g);
  const bf16x8 qC1 = *(const bf16x8*)(Qp + 32 * DM + 32 + 8 * g);
  const bf16x8 qD0 = *(const bf16x8*)(Qp + 48 * DM + 8 * g);
  const bf16x8 qD1 = *(const bf16x8*)(Qp + 48 * DM + 32 + 8 * g);

  float ssA[4], ssB[4], ssC[4], ssD[4];
#pragma unroll
  for (int i = 0; i < 4; i++) { ssA[i] = 0.f; ssB[i] = 0.f; ssC[i] = 0.f; ssD[i] = 0.f; }
  f32x4 oA[4], oB[4], oC[4], oD[4];
#pragma unroll
  for (int f = 0; f < 4; f++) {
    oA[f] = (f32x4){0.f, 0.f, 0.f, 0.f};
    oB[f] = (f32x4){0.f, 0.f, 0.f, 0.f};
    oC[f] = (f32x4){0.f, 0.f, 0.f, 0.f};
    oD[f] = (f32x4){0.f, 0.f, 0.f, 0.f};
  }

  const int xA = (g ^ (qi & 7)) * 8;
  const int xB = ((4 + g) ^ (qi & 7)) * 8;

#define SM_PACK(S0, S1, SS, PB)                                               \
  bf16x8 PB;                                                                  \
  {                                                                           \
    float e0_[4], e1_[4];                                                     \
    _Pragma("unroll") for (int r = 0; r < 4; r++) {                           \
      e0_[r] = exp2_fast(S0[r]);                                              \
      e1_[r] = exp2_fast(S1[r]);                                              \
      SS[r] += e0_[r] + e1_[r];                                               \
    }                                                                         \
    u32x4 pw_;                                                                \
    _Pragma("unroll") for (int r = 0; r < 4; r++)                             \
        pw_[r] = cvt_pk_bf16(e0_[r], e1_[r]);                                 \
    PB = __builtin_bit_cast(bf16x8, pw_);                                     \
  }

  auto tile = [&](const short* Ks, const short* Vs) {
#pragma unroll
    for (int s = 0; s < 2; s++) {
      const int r0 = (32 * s + 2 * qi) * 64;
      const bf16x8 k00 = *(const bf16x8*)&Ks[r0 + xA];
      const bf16x8 k01 = *(const bf16x8*)&Ks[r0 + xB];
      const bf16x8 k10 = *(const bf16x8*)&Ks[r0 + 64 + xA];
      const bf16x8 k11 = *(const bf16x8*)&Ks[r0 + 64 + xB];

      f32x4 sA0 = (f32x4){0.f, 0.f, 0.f, 0.f}, sA1 = sA0;
      f32x4 sB0 = sA0, sB1 = sA0, sC0 = sA0, sC1 = sA0, sD0 = sA0, sD1 = sA0;
      __builtin_amdgcn_s_setprio(1);
      sA0 = __builtin_amdgcn_mfma_f32_16x16x32_bf16(k00, qA0, sA0, 0, 0, 0);
      sA0 = __builtin_amdgcn_mfma_f32_16x16x32_bf16(k01, qA1, sA0, 0, 0, 0);
      sA1 = __builtin_amdgcn_mfma_f32_16x16x32_bf16(k10, qA0, sA1, 0, 0, 0);
      sA1 = __builtin_amdgcn_mfma_f32_16x16x32_bf16(k11, qA1, sA1, 0, 0, 0);
      sB0 = __builtin_amdgcn_mfma_f32_16x16x32_bf16(k00, qB0, sB0, 0, 0, 0);
      sB0 = __builtin_amdgcn_mfma_f32_16x16x32_bf16(k01, qB1, sB0, 0, 0, 0);
      sB1 = __builtin_amdgcn_mfma_f32_16x16x32_bf16(k10, qB0, sB1, 0, 0, 0);
      sB1 = __builtin_amdgcn_mfma_f32_16x16x32_bf16(k11, qB1, sB1, 0, 0, 0);
      sC0 = __builtin_amdgcn_mfma_f32_16x16x32_bf16(k00, qC0, sC0, 0, 0, 0);
      sC0 = __builtin_amdgcn_mfma_f32_16x16x32_bf16(k01, qC1, sC0, 0, 0, 0);
      sC1 = __builtin_amdgcn_mfma_f32_16x16x32_bf16(k10, qC0, sC1, 0, 0, 0);
      sC1 = __builtin_amdgcn_mfma_f32_16x16x32_bf16(k11, qC1, sC1, 0, 0, 0);
      sD0 = __builtin_amdgcn_mfma_f32_16x16x32_bf16(k00, qD0, sD0, 0, 0, 0);
      sD0 = __builtin_amdgcn_mfma_f32_16x16x32_bf16(k01, qD1, sD0, 0, 0, 0);
      sD1 = __builtin_amdgcn_mfma_f32_16x16x32_bf16(k10, qD0, sD1, 0, 0, 0);
      sD1 = __builtin_amdgcn_mfma_f32_16x16x32_bf16(k11, qD1, sD1, 0, 0, 0);
      __builtin_amdgcn_s_setprio(0);

      SM_PACK(sA0, sA1, ssA, pbA)
      SM_PACK(sB0, sB1, ssB, pbB)
      SM_PACK(sC0, sC1, ssC, pbC)
      SM_PACK(sD0, sD1, ssD, pbD)

      const int vx = ((4 * s + g) ^ (qi & 7)) * 8;
      __builtin_amdgcn_s_setprio(1);
#pragma unroll
      for (int f = 0; f < 4; f++) {
        const bf16x8 vv = *(const bf16x8*)&Vs[(qi + 16 * f) * 64 + vx];
        oA[f] = __builtin_amdgcn_mfma_f32_16x16x32_bf16(vv, pbA, oA[f], 0, 0, 0);
        oB[f] = __builtin_amdgcn_mfma_f32_16x16x32_bf16(vv, pbB, oB[f], 0, 0, 0);
        oC[f] = __builtin_amdgcn_mfma_f32_16x16x32_bf16(vv, pbC, oC[f], 0, 0, 0);
        oD[f] = __builtin_amdgcn_mfma_f32_16x16x32_bf16(vv, pbD, oD[f], 0, 0, 0);
      }
      __builtin_amdgcn_s_setprio(0);
    }
  };

  STAGE(0, 0);
  for (int t = 0; t < 32; ++t) {
    __syncthreads();  // drains stage [vmcnt0] + prev buf reads [lgkm]
    if (t < 31) STAGE((t + 1) & 1, (t + 1) * 64);
    tile(&lds[t & 1][0], &lds[t & 1][4096]);
  }

#define WRITE_G(SS, O, ROWOFF)                                                \
  {                                                                           \
    float ss_ = (SS[0] + SS[1]) + (SS[2] + SS[3]);                            \
    ss_ += __shfl_xor(ss_, 16);                                               \
    ss_ += __shfl_xor(ss_, 32);                                               \
    const float inv_ = 1.f / ss_;                                             \
    short* Op_ = attn + (bbS + rowA + (ROWOFF)) * DM + h * DH;                \
    _Pragma("unroll") for (int f = 0; f < 4; f++) {                           \
      ushort4 v_;                                                             \
      v_.x = (unsigned short)f2bf(O[f][0] * inv_);                            \
      v_.y = (unsigned short)f2bf(O[f][1] * inv_);                            \
      v_.z = (unsigned short)f2bf(O[f][2] * inv_);                            \
      v_.w = (unsigned short)f2bf(O[f][3] * inv_);                            \
      *(ushort4*)(Op_ + f * 16 + g * 4) = v_;                                 \
    }                                                                         \
  }

  WRITE_G(ssA, oA, 0)
  WRITE_G(ssB, oB, 16)
  WRITE_G(ssC, oC, 32)
  WRITE_G(ssD, oD, 48)
#undef STAGE
#undef SM_PACK
#undef WRITE_G
}

// ---------------------------------------------------------------- layernorm
__global__ __launch_bounds__(256) void k_ln(const float* __restrict__ q,
                                            const short* __restrict__ om,
                                            const float* __restrict__ gamma,
                                            const float* __restrict__ beta,
                                            float* __restrict__ out) {
  const int row = blockIdx.x;
  const int t = threadIdx.x;
  const int w = t >> 6, l = t & 63;
  const size_t base = (size_t)row * DM + t * 4;
  const float4 qv = *(const float4*)(q + base);
  const ushort4 ov = *(const ushort4*)(om + base);
  float v[4];
  v[0] = qv.x + bf2f((short)ov.x);
  v[1] = qv.y + bf2f((short)ov.y);
  v[2] = qv.z + bf2f((short)ov.z);
  v[3] = qv.w + bf2f((short)ov.w);
  float s = v[0] + v[1] + v[2] + v[3];
  float s2 = v[0] * v[0] + v[1] * v[1] + v[2] * v[2] + v[3] * v[3];
#pragma unroll
  for (int off = 32; off >= 1; off >>= 1) {
    s += __shfl_xor(s, off);
    s2 += __shfl_xor(s2, off);
  }
  __shared__ float ps[4], ps2[4];
  if (l == 0) {
    ps[w] = s;
    ps2[w] = s2;
  }
  __syncthreads();
  const float St = ps[0] + ps[1] + ps[2] + ps[3];
  const float S2t = ps2[0] + ps2[1] + ps2[2] + ps2[3];
  const float mu = St * (1.f / 1024.f);
  float var = S2t * (1.f / 1024.f) - mu * mu;
  const float rstd = rsqrtf(var + 1e-5f);
  const float4 gv = *(const float4*)(gamma + t * 4);
  const float4 bv = *(const float4*)(beta + t * 4);
  float4 ovv;
  ovv.x = (v[0] - mu) * rstd * gv.x + bv.x;
  ovv.y = (v[1] - mu) * rstd * gv.y + bv.y;
  ovv.z = (v[2] - mu) * rstd * gv.z + bv.z;
  ovv.w = (v[3] - mu) * rstd * gv.w + bv.w;
  *(float4*)(out + base) = ovv;
}

// ---------------------------------------------------------------- launch
extern "C" void kernel_launch(void* const* d_in, const int* in_sizes, int n_in,
                              void* d_out, int out_size, void* d_ws, size_t ws_size,
                              hipStream_t stream) {
  const float* q = (const float*)d_in[0];
  const float* kv = (const float*)d_in[1];
  const float* Wq = (const float*)d_in[2];
  const float* bq = (const float*)d_in[3];
  const float* Wk = (const float*)d_in[4];
  const float* bk = (const float*)d_in[5];
  const float* Wv = (const float*)d_in[6];
  const float* bv = (const float*)d_in[7];
  const float* Wo = (const float*)d_in[8];
  const float* bo = (const float*)d_in[9];
  const float* gamma = (const float*)d_in[10];
  const float* beta = (const float*)d_in[11];

  short* ws = (short*)d_ws;
  short* Wt = ws;                        // 4 * 1Mi shorts (Wq^T,Wk^T,Wv^T,Wo^T)
  short* qb16 = ws + 4u * 1048576u;      // bf16(q); later attn out
  short* kvb16 = qb16 + 4194304u;        // bf16(kv); later om
  short* qm = kvb16 + 4194304u;          // [4096,1024] bf16 (pre-scaled)
  short* km = qm + 4194304u;             // [4096,1024] bf16
  short* vtb = km + 4194304u;            // [B,H,64,S] bf16
  short* attnb = qb16;
  short* om = kvb16;

  hipLaunchKernelGGL(k_transpose, dim3(32, 32, 4), dim3(32, 8), 0, stream,
                     Wq, Wk, Wv, Wo, Wt);
  hipLaunchKernelGGL(k_cvt, dim3(4096), dim3(256), 0, stream, q, kv, qb16, kvb16);
  hipLaunchKernelGGL(k_gemm_qkv, dim3(8, 32, 3), dim3(256), 0, stream,
                     qb16, kvb16, Wt, bq, bk, bv, qm, km, vtb);
  hipLaunchKernelGGL(k_attn, dim3(512), dim3(128), 0, stream,
                     qm, km, vtb, attnb);
  hipLaunchKernelGGL(k_gemm_o, dim3(8, 32, 1), dim3(256), 0, stream,
                     attnb, Wt + 3u * 1048576u, bo, om);
  hipLaunchKernelGGL(k_ln, dim3(4096), dim3(256), 0, stream,
                     q, om, gamma, beta, (float*)d_out);
}

// Round 12
// 135.958 us; speedup vs baseline: 1.2055x; 1.2055x over previous
//
#include <hip/hip_runtime.h>
#include <hip/hip_bf16.h>

// B=2, S=2048, D_MODEL=1024, H=16, D_HEAD=64. I/O: float32 (per reference).
// Internal intermediates bf16. Pipeline:
//   Wt = bf16(transpose(W)) x4; qb16/kvb16 = bf16(q/kv)
//   qm = bf16((qb16@Wq+bq)*log2e/8), km = bf16(kvb16@Wk+bk), vt = (kvb16@Wv+bv)^T per head
//   attn partials: key-split x2 (no-max softmax => additive): Op0/Op1 bf16 + ss f32
//   combine: attn = (Op0+Op1)/(ss0+ss1) -> qm region (dead after attn)
//   om = bf16(attn@Wo+bo)   (kvb16 region)
//   out = f32 LayerNorm(q+om)*gamma+beta
// Attn block = R8-proven: 8 waves x 32 q-rows (G=2 q-groups sharing K/V LDS
// reads), 3-buf counted-vmcnt pipeline; now 512 blocks (2/CU -> 4 waves/SIMD)
// each covering half the keys (16 of 32 tiles).

#define DM 1024
#define SEQ 2048
#define NB 2
#define NH 16
#define DH 64

typedef __attribute__((ext_vector_type(8))) short bf16x8;
typedef __attribute__((ext_vector_type(4))) float f32x4;
typedef __attribute__((ext_vector_type(4))) unsigned int u32x4;

__device__ __forceinline__ float bf2f(short s) {
  unsigned u = ((unsigned)(unsigned short)s) << 16;
  return __builtin_bit_cast(float, u);
}
__device__ __forceinline__ short f2bf(float f) {
  unsigned u = __builtin_bit_cast(unsigned, f);
  u += 0x7fffu + ((u >> 16) & 1u);  // RNE
  return (short)(u >> 16);
}
__device__ __forceinline__ unsigned cvt_pk_bf16(float lo, float hi) {
  unsigned r;
  asm("v_cvt_pk_bf16_f32 %0, %1, %2" : "=v"(r) : "v"(lo), "v"(hi));
  return r;
}
__device__ __forceinline__ float exp2_fast(float x) {
  float r;
  asm("v_exp_f32 %0, %1" : "=v"(r) : "v"(x));
  return r;
}

#define GLL16(gsrc, ldst)                                                     \
  __builtin_amdgcn_global_load_lds(                                           \
      (const __attribute__((address_space(1))) void*)(gsrc),                  \
      (__attribute__((address_space(3))) void*)(ldst), 16, 0, 0)

#define WAIT_VM(N)                                                            \
  asm volatile("s_waitcnt vmcnt(" #N ")" ::: "memory");                       \
  __builtin_amdgcn_s_barrier();                                               \
  __builtin_amdgcn_sched_barrier(0)

// ---------------------------------------------------------------- transpose
__global__ __launch_bounds__(256) void k_transpose(
    const float* __restrict__ Wq, const float* __restrict__ Wk,
    const float* __restrict__ Wv, const float* __restrict__ Wo,
    short* __restrict__ Wt_all) {
  const int z = blockIdx.z;
  const float* src = (z == 0) ? Wq : (z == 1) ? Wk : (z == 2) ? Wv : Wo;
  short* dst = Wt_all + (size_t)z * (DM * DM);
  __shared__ float t[32][33];
  const int n0 = blockIdx.x * 32, k0 = blockIdx.y * 32;
  const int tx = threadIdx.x, ty = threadIdx.y;  // (32,8)
#pragma unroll
  for (int i = 0; i < 32; i += 8)
    t[ty + i][tx] = src[(size_t)(k0 + ty + i) * DM + n0 + tx];
  __syncthreads();
#pragma unroll
  for (int i = 0; i < 32; i += 8)
    dst[(size_t)(n0 + ty + i) * DM + k0 + tx] = f2bf(t[tx][ty + i]);
}

// ---------------------------------------------------------------- f32->bf16
__global__ __launch_bounds__(256) void k_cvt(const float* __restrict__ q,
                                             const float* __restrict__ kv,
                                             short* __restrict__ qb,
                                             short* __restrict__ kvb) {
  const int i = blockIdx.x * 256 + threadIdx.x;
  const int half = 524288;
  const float* src = (i < half) ? q : kv;
  short* dst = (i < half) ? qb : kvb;
  const size_t j = (size_t)((i < half) ? i : i - half) * 8;
  const float4 a = *(const float4*)(src + j);
  const float4 b = *(const float4*)(src + j + 4);
  u32x4 pw;
  pw[0] = cvt_pk_bf16(a.x, a.y);
  pw[1] = cvt_pk_bf16(a.z, a.w);
  pw[2] = cvt_pk_bf16(b.x, b.y);
  pw[3] = cvt_pk_bf16(b.z, b.w);
  *(bf16x8*)(dst + j) = __builtin_bit_cast(bf16x8, pw);
}

// ---------------------------------------------------------------- GEMM body
// C[m,n] = (sum_k A[m,k]*Wt[n,k] + bias[n]) * cscale; M=4096, N=K=1024.
// 128x128 tile, BK=32, 4 waves, 4x4 frags of 16x16x32. 2-buffer LDS (32KB),
// one __syncthreads per K-step, stage-next after the barrier.
__device__ __forceinline__ void gemm_body32(short (*As)[4096], short (*Bs)[4096],
                                            const short* __restrict__ X,
                                            const short* __restrict__ Wt,
                                            const float* __restrict__ bias,
                                            short* __restrict__ out,
                                            int vt_mode, float cscale,
                                            int bx, int by) {
  const int tid = threadIdx.x;
  const int w = tid >> 6, l = tid & 63;
  const int g = l >> 4, qi = l & 15;
  const int n0 = bx * 128;
  const int m0 = by * 128;
  const int wr = w >> 1, wc = w & 1;

  f32x4 acc[4][4];
#pragma unroll
  for (int m = 0; m < 4; m++)
#pragma unroll
    for (int n = 0; n < 4; n++) acc[m][n] = (f32x4){0.f, 0.f, 0.f, 0.f};

  const int srow = w * 16 + (l >> 2);
  const int scol = ((l & 3) ^ ((l >> 2) & 3)) * 8;
  const short* Ag = X + (size_t)(m0 + srow) * DM + scol;
  const short* Bg = Wt + (size_t)(n0 + srow) * DM + scol;

  auto stage = [&](int buf, int k0) {
#pragma unroll
    for (int jj = 0; jj < 2; ++jj) {
      GLL16(Ag + (size_t)(jj * 64) * DM + k0, &As[buf][jj * 2048 + w * 512]);
      GLL16(Bg + (size_t)(jj * 64) * DM + k0, &Bs[buf][jj * 2048 + w * 512]);
    }
  };

  auto compute = [&](int buf) {
    bf16x8 a[4], b[4];
    const int xo = (g ^ (qi & 3)) * 8;
#pragma unroll
    for (int m = 0; m < 4; m++)
      a[m] = *(const bf16x8*)&As[buf][(wr * 64 + m * 16 + qi) * 32 + xo];
#pragma unroll
    for (int n = 0; n < 4; n++)
      b[n] = *(const bf16x8*)&Bs[buf][(wc * 64 + n * 16 + qi) * 32 + xo];
    __builtin_amdgcn_s_setprio(1);
#pragma unroll
    for (int m = 0; m < 4; m++)
#pragma unroll
      for (int n = 0; n < 4; n++)
        acc[m][n] = __builtin_amdgcn_mfma_f32_16x16x32_bf16(a[m], b[n],
                                                            acc[m][n], 0, 0, 0);
    __builtin_amdgcn_s_setprio(0);
  };

  stage(0, 0);
  for (int ks = 0; ks < 32; ++ks) {
    __syncthreads();
    if (ks < 31) stage((ks + 1) & 1, (ks + 1) * 32);
    compute(ks & 1);
  }

  const int col0 = n0 + wc * 64;
  const int row0 = m0 + wr * 64;
  float bfv[4];
#pragma unroll
  for (int n = 0; n < 4; n++) bfv[n] = bias[col0 + n * 16 + qi];

  if (!vt_mode) {
#pragma unroll
    for (int m = 0; m < 4; m++) {
#pragma unroll
      for (int n = 0; n < 4; n++) {
        const int col = col0 + n * 16 + qi;
#pragma unroll
        for (int r = 0; r < 4; r++) {
          const int row = row0 + m * 16 + g * 4 + r;
          out[(size_t)row * DM + col] = f2bf((acc[m][n][r] + bfv[n]) * cscale);
        }
      }
    }
  } else {
#pragma unroll
    for (int m = 0; m < 4; m++) {
      const int s_base = row0 + m * 16 + g * 4;
      const int bb = s_base >> 11;
      const int s = s_base & (SEQ - 1);
#pragma unroll
      for (int n = 0; n < 4; n++) {
        const int col = col0 + n * 16 + qi;
        const int h = col >> 6, d = col & 63;
        ushort4 v;
        v.x = (unsigned short)f2bf(acc[m][n][0] + bfv[n]);
        v.y = (unsigned short)f2bf(acc[m][n][1] + bfv[n]);
        v.z = (unsigned short)f2bf(acc[m][n][2] + bfv[n]);
        v.w = (unsigned short)f2bf(acc[m][n][3] + bfv[n]);
        *(ushort4*)&out[(((size_t)bb * NH + h) * DH + d) * SEQ + s] = v;
      }
    }
  }
}

__device__ __forceinline__ void xcd_remap(int& bx, int& by) {
  const int lin2 = blockIdx.x + 8 * blockIdx.y;
  const int xcd = lin2 & 7, jj = lin2 >> 3;
  bx = jj & 7;
  by = xcd * 4 + (jj >> 3);
}

__global__ __launch_bounds__(256) void k_gemm_qkv(
    const short* __restrict__ qb, const short* __restrict__ kvb,
    const short* __restrict__ Wt, const float* __restrict__ bq,
    const float* __restrict__ bk, const float* __restrict__ bv,
    short* __restrict__ qm, short* __restrict__ km, short* __restrict__ vtb) {
  __shared__ short As[2][4096], Bs[2][4096];
  const int z = blockIdx.z;
  const short* X = (z == 0) ? qb : kvb;
  const short* W = Wt + (size_t)z * (DM * DM);
  const float* bias = (z == 0) ? bq : (z == 1) ? bk : bv;
  short* out = (z == 0) ? qm : (z == 1) ? km : vtb;
  const float cs = (z == 0) ? 0.18033688011112042f : 1.0f;  // log2e/8
  int bx, by;
  xcd_remap(bx, by);
  gemm_body32(As, Bs, X, W, bias, out, z == 2, cs, bx, by);
}

__global__ __launch_bounds__(256) void k_gemm_o(
    const short* __restrict__ attn, const short* __restrict__ Wto,
    const float* __restrict__ bo, short* __restrict__ om) {
  __shared__ short As[2][4096], Bs[2][4096];
  int bx, by;
  xcd_remap(bx, by);
  gemm_body32(As, Bs, attn, Wto, bo, om, 0, 1.0f, bx, by);
}

// ---------------------------------------------------------------- attention
// R8-proven block: 8 waves x 32 q-rows (G=2 q-groups sharing K/V LDS reads)
// = 256 q-rows of one (b,h); KEY-SPLIT x2: 512 blocks (2/CU -> 16 waves/CU),
// each covers keys [half*1024, half*1024+1024) = 16 tiles. 3 LDS buffers,
// depth-2 prefetch, counted vmcnt(2)+s_barrier per tile; last tile peeled at
// vmcnt(0). No-max softmax -> partials additive: write un-normalized bf16 O
// and f32 row-sum ss; k_combine finishes.
__global__ __launch_bounds__(512) void k_attn(const short* __restrict__ qm,
                                              const short* __restrict__ km,
                                              const short* __restrict__ vt,
                                              short* __restrict__ Op0,
                                              short* __restrict__ Op1,
                                              float* __restrict__ ssf) {
  __shared__ short lds[3][8192];  // per buf: K [0..4095], V^T [4096..8191]

  // 512 blocks: xcd = lin&7 gets 4 whole (b,h) pairs (16 sub-blocks each).
  const int lin = blockIdx.x;
  const int xcd = lin & 7, j = lin >> 3;   // j 0..63
  const int pair = xcd + 8 * (j >> 4);     // 4 pairs per xcd
  const int sub = j & 15;
  const int qb = sub >> 1, half = sub & 1;
  const int h = pair & 15, bb = pair >> 4;
  const int q0 = qb * 256;
  const int keybase = half * 1024;

  const int tid = threadIdx.x;
  const int w = tid >> 6, l = tid & 63;
  const int g = l >> 4, qi = l & 15;

  const size_t bbS = (size_t)bb * SEQ;
  const size_t vbase = ((size_t)(bb * NH + h)) * DH * SEQ;
  const short* __restrict__ kmh = km + bbS * DM + h * DH;

  // staging lane constants (512 thr: row tid>>3 = 0..63, slot tid&7)
  const int skey = tid >> 3;
  const int sslot = tid & 7;
  const int kgq = sslot ^ ((skey >> 1) & 7);  // K dim-block at this slot
  const int vkb = sslot ^ (skey & 7);         // V key-block at this slot
  const short* __restrict__ srcK0 = kmh + (size_t)skey * DM + kgq * 8;
  const short* __restrict__ srcV0 = vt + vbase + (size_t)skey * SEQ + vkb * 8;

#define STAGE(buf, kk0)                                                       \
  {                                                                           \
    GLL16(srcK0 + (size_t)(kk0)*DM, &lds[buf][w * 512]);                      \
    GLL16(srcV0 + (kk0), &lds[buf][4096 + w * 512]);                          \
  }

  // Q fragments (2 q-groups: rows rowA, rowA+16), pre-scaled by log2e/8
  const int rowA = q0 + w * 32 + qi;
  const short* QpA = qm + (bbS + rowA) * DM + h * DH;
  const bf16x8 qA0 = *(const bf16x8*)(QpA + 8 * g);
  const bf16x8 qA1 = *(const bf16x8*)(QpA + 32 + 8 * g);
  const bf16x8 qB0 = *(const bf16x8*)(QpA + 16 * DM + 8 * g);
  const bf16x8 qB1 = *(const bf16x8*)(QpA + 16 * DM + 32 + 8 * g);

  float ssA[4], ssB[4];
#pragma unroll
  for (int i = 0; i < 4; i++) { ssA[i] = 0.f; ssB[i] = 0.f; }
  f32x4 oA[4], oB[4];
#pragma unroll
  for (int f = 0; f < 4; f++) {
    oA[f] = (f32x4){0.f, 0.f, 0.f, 0.f};
    oB[f] = (f32x4){0.f, 0.f, 0.f, 0.f};
  }

  const int xA = (g ^ (qi & 7)) * 8;
  const int xB = ((4 + g) ^ (qi & 7)) * 8;

  auto tile = [&](const short* Ks, const short* Vs) {
#pragma unroll
    for (int s = 0; s < 2; s++) {
      const int r0 = (32 * s + 2 * qi) * 64;
      const bf16x8 k00 = *(const bf16x8*)&Ks[r0 + xA];
      const bf16x8 k01 = *(const bf16x8*)&Ks[r0 + xB];
      const bf16x8 k10 = *(const bf16x8*)&Ks[r0 + 64 + xA];
      const bf16x8 k11 = *(const bf16x8*)&Ks[r0 + 64 + xB];

      f32x4 sA0 = (f32x4){0.f, 0.f, 0.f, 0.f};
      f32x4 sA1 = (f32x4){0.f, 0.f, 0.f, 0.f};
      f32x4 sB0 = (f32x4){0.f, 0.f, 0.f, 0.f};
      f32x4 sB1 = (f32x4){0.f, 0.f, 0.f, 0.f};
      __builtin_amdgcn_s_setprio(1);
      sA0 = __builtin_amdgcn_mfma_f32_16x16x32_bf16(k00, qA0, sA0, 0, 0, 0);
      sA0 = __builtin_amdgcn_mfma_f32_16x16x32_bf16(k01, qA1, sA0, 0, 0, 0);
      sA1 = __builtin_amdgcn_mfma_f32_16x16x32_bf16(k10, qA0, sA1, 0, 0, 0);
      sA1 = __builtin_amdgcn_mfma_f32_16x16x32_bf16(k11, qA1, sA1, 0, 0, 0);
      sB0 = __builtin_amdgcn_mfma_f32_16x16x32_bf16(k00, qB0, sB0, 0, 0, 0);
      sB0 = __builtin_amdgcn_mfma_f32_16x16x32_bf16(k01, qB1, sB0, 0, 0, 0);
      sB1 = __builtin_amdgcn_mfma_f32_16x16x32_bf16(k10, qB0, sB1, 0, 0, 0);
      sB1 = __builtin_amdgcn_mfma_f32_16x16x32_bf16(k11, qB1, sB1, 0, 0, 0);
      __builtin_amdgcn_s_setprio(0);

      // P = exp2(score); no max subtraction (bounded scores)
      float eA0[4], eA1[4], eB0[4], eB1[4];
#pragma unroll
      for (int r = 0; r < 4; r++) {
        eA0[r] = exp2_fast(sA0[r]);
        eA1[r] = exp2_fast(sA1[r]);
        eB0[r] = exp2_fast(sB0[r]);
        eB1[r] = exp2_fast(sB1[r]);
      }
#pragma unroll
      for (int r = 0; r < 4; r++) {
        ssA[r] += eA0[r] + eA1[r];
        ssB[r] += eB0[r] + eB1[r];
      }
      u32x4 pwA, pwB;
#pragma unroll
      for (int r = 0; r < 4; r++) {
        pwA[r] = cvt_pk_bf16(eA0[r], eA1[r]);
        pwB[r] = cvt_pk_bf16(eB0[r], eB1[r]);
      }
      const bf16x8 pbA = __builtin_bit_cast(bf16x8, pwA);
      const bf16x8 pbB = __builtin_bit_cast(bf16x8, pwB);

      const int vx = ((4 * s + g) ^ (qi & 7)) * 8;
      __builtin_amdgcn_s_setprio(1);
#pragma unroll
      for (int f = 0; f < 4; f++) {
        const bf16x8 vv = *(const bf16x8*)&Vs[(qi + 16 * f) * 64 + vx];
        oA[f] = __builtin_amdgcn_mfma_f32_16x16x32_bf16(vv, pbA, oA[f], 0, 0, 0);
        oB[f] = __builtin_amdgcn_mfma_f32_16x16x32_bf16(vv, pbB, oB[f], 0, 0, 0);
      }
      __builtin_amdgcn_s_setprio(0);
    }
  };

  STAGE(0, keybase);
  STAGE(1, keybase + 64);
  int cur = 0;
  for (int t = 0; t < 15; ++t) {
    WAIT_VM(2);  // tile t's 2 loads done; t+1's stay in flight
    if (t < 14) {
      int n2 = cur + 2;
      if (n2 >= 3) n2 -= 3;
      STAGE(n2, keybase + (t + 2) * 64);
    }
    tile(&lds[cur][0], &lds[cur][4096]);
    cur = (cur + 1 == 3) ? 0 : cur + 1;
  }
  WAIT_VM(0);  // peeled last tile
  tile(&lds[cur][0], &lds[cur][4096]);

  short* Opb = half ? Op1 : Op0;

#define WRITE_P(SS, O, ROWOFF)                                                \
  {                                                                           \
    float ss_ = (SS[0] + SS[1]) + (SS[2] + SS[3]);                            \
    ss_ += __shfl_xor(ss_, 16);                                               \
    ss_ += __shfl_xor(ss_, 32);                                               \
    if (g == 0)                                                               \
      ssf[(size_t)(half * 16 + h) * 4096 + bb * SEQ + rowA + (ROWOFF)] = ss_; \
    short* Op_ = Opb + (bbS + rowA + (ROWOFF)) * DM + h * DH;                 \
    _Pragma("unroll") for (int f = 0; f < 4; f++) {                           \
      ushort4 v_;                                                             \
      v_.x = (unsigned short)f2bf(O[f][0]);                                   \
      v_.y = (unsigned short)f2bf(O[f][1]);                                   \
      v_.z = (unsigned short)f2bf(O[f][2]);                                   \
      v_.w = (unsigned short)f2bf(O[f][3]);                                   \
      *(ushort4*)(Op_ + f * 16 + g * 4) = v_;                                 \
    }                                                                         \
  }

  WRITE_P(ssA, oA, 0)
  WRITE_P(ssB, oB, 16)
#undef STAGE
#undef WRITE_P
}

// ---------------------------------------------------------------- combine
// attn[row][col] = (Op0+Op1) / (ss0+ss1), head h = col>>6.
__global__ __launch_bounds__(256) void k_combine(const short* __restrict__ Op0,
                                                 const short* __restrict__ Op1,
                                                 const float* __restrict__ ssf,
                                                 short* __restrict__ out) {
  const int row = blockIdx.x;        // 0..4095 (global: bb*2048 + r)
  const int t = threadIdx.x;
  const int col = t * 4;
  const int h = col >> 6;
  const float s0 = ssf[(size_t)h * 4096 + row];
  const float s1 = ssf[(size_t)(16 + h) * 4096 + row];
  const float inv = 1.f / (s0 + s1);
  const size_t idx = (size_t)row * DM + col;
  const ushort4 a = *(const ushort4*)(Op0 + idx);
  const ushort4 b = *(const ushort4*)(Op1 + idx);
  ushort4 o;
  o.x = (unsigned short)f2bf((bf2f((short)a.x) + bf2f((short)b.x)) * inv);
  o.y = (unsigned short)f2bf((bf2f((short)a.y) + bf2f((short)b.y)) * inv);
  o.z = (unsigned short)f2bf((bf2f((short)a.z) + bf2f((short)b.z)) * inv);
  o.w = (unsigned short)f2bf((bf2f((short)a.w) + bf2f((short)b.w)) * inv);
  *(ushort4*)(out + idx) = o;
}

// ---------------------------------------------------------------- layernorm
__global__ __launch_bounds__(256) void k_ln(const float* __restrict__ q,
                                            const short* __restrict__ om,
                                            const float* __restrict__ gamma,
                                            const float* __restrict__ beta,
                                            float* __restrict__ out) {
  const int row = blockIdx.x;
  const int t = threadIdx.x;
  const int w = t >> 6, l = t & 63;
  const size_t base = (size_t)row * DM + t * 4;
  const float4 qv = *(const float4*)(q + base);
  const ushort4 ov = *(const ushort4*)(om + base);
  float v[4];
  v[0] = qv.x + bf2f((short)ov.x);
  v[1] = qv.y + bf2f((short)ov.y);
  v[2] = qv.z + bf2f((short)ov.z);
  v[3] = qv.w + bf2f((short)ov.w);
  float s = v[0] + v[1] + v[2] + v[3];
  float s2 = v[0] * v[0] + v[1] * v[1] + v[2] * v[2] + v[3] * v[3];
#pragma unroll
  for (int off = 32; off >= 1; off >>= 1) {
    s += __shfl_xor(s, off);
    s2 += __shfl_xor(s2, off);
  }
  __shared__ float ps[4], ps2[4];
  if (l == 0) {
    ps[w] = s;
    ps2[w] = s2;
  }
  __syncthreads();
  const float St = ps[0] + ps[1] + ps[2] + ps[3];
  const float S2t = ps2[0] + ps2[1] + ps2[2] + ps2[3];
  const float mu = St * (1.f / 1024.f);
  float var = S2t * (1.f / 1024.f) - mu * mu;
  const float rstd = rsqrtf(var + 1e-5f);
  const float4 gv = *(const float4*)(gamma + t * 4);
  const float4 bv = *(const float4*)(beta + t * 4);
  float4 ovv;
  ovv.x = (v[0] - mu) * rstd * gv.x + bv.x;
  ovv.y = (v[1] - mu) * rstd * gv.y + bv.y;
  ovv.z = (v[2] - mu) * rstd * gv.z + bv.z;
  ovv.w = (v[3] - mu) * rstd * gv.w + bv.w;
  *(float4*)(out + base) = ovv;
}

// ---------------------------------------------------------------- launch
extern "C" void kernel_launch(void* const* d_in, const int* in_sizes, int n_in,
                              void* d_out, int out_size, void* d_ws, size_t ws_size,
                              hipStream_t stream) {
  const float* q = (const float*)d_in[0];
  const float* kv = (const float*)d_in[1];
  const float* Wq = (const float*)d_in[2];
  const float* bq = (const float*)d_in[3];
  const float* Wk = (const float*)d_in[4];
  const float* bk = (const float*)d_in[5];
  const float* Wv = (const float*)d_in[6];
  const float* bv = (const float*)d_in[7];
  const float* Wo = (const float*)d_in[8];
  const float* bo = (const float*)d_in[9];
  const float* gamma = (const float*)d_in[10];
  const float* beta = (const float*)d_in[11];

  short* ws = (short*)d_ws;
  short* Wt = ws;                        // 4 * 1Mi shorts (Wq^T,Wk^T,Wv^T,Wo^T)
  short* qb16 = ws + 4u * 1048576u;      // bf16(q); later attn O-partial half0
  short* kvb16 = qb16 + 4194304u;        // bf16(kv); later O-partial half1; then om
  short* qm = kvb16 + 4194304u;          // pre-scaled Q; later combined attn
  short* km = qm + 4194304u;             // [4096,1024] bf16
  short* vtb = km + 4194304u;            // [B,H,64,S] bf16
  float* ssf = (float*)ws;               // ss partials (Wq^T region, dead by then)
  short* om = kvb16;                     // om aliases kvb16 (dead after combine)

  hipLaunchKernelGGL(k_transpose, dim3(32, 32, 4), dim3(32, 8), 0, stream,
                     Wq, Wk, Wv, Wo, Wt);
  hipLaunchKernelGGL(k_cvt, dim3(4096), dim3(256), 0, stream, q, kv, qb16, kvb16);
  hipLaunchKernelGGL(k_gemm_qkv, dim3(8, 32, 3), dim3(256), 0, stream,
                     qb16, kvb16, Wt, bq, bk, bv, qm, km, vtb);
  hipLaunchKernelGGL(k_attn, dim3(512), dim3(512), 0, stream,
                     qm, km, vtb, qb16, kvb16, ssf);
  hipLaunchKernelGGL(k_combine, dim3(4096), dim3(256), 0, stream,
                     qb16, kvb16, ssf, qm);
  hipLaunchKernelGGL(k_gemm_o, dim3(8, 32, 1), dim3(256), 0, stream,
                     qm, Wt + 3u * 1048576u, bo, om);
  hipLaunchKernelGGL(k_ln, dim3(4096), dim3(256), 0, stream,
                     q, om, gamma, beta, (float*)d_out);
}

// Round 13
// 128.103 us; speedup vs baseline: 1.2794x; 1.0613x over previous
//
#include <hip/hip_runtime.h>
#include <hip/hip_bf16.h>

// B=2, S=2048, D_MODEL=1024, H=16, D_HEAD=64. I/O: float32 (per reference).
// Internal intermediates bf16. Pipeline (R8-proven config):
//   Wt = bf16(transpose(W)) x4; qb16/kvb16 = bf16(q/kv)
//   qm = bf16((qb16@Wq+bq)*log2e/8), km = bf16(kvb16@Wk+bk), vt = (kvb16@Wv+bv)^T per head
//   attn = flash-attention(qm,km,vt) merged heads [4096,1024] bf16   (aliases qb16)
//   om = bf16(attn@Wo+bo)                                            (aliases kvb16)
//   out = f32 LayerNorm(q+om)*gamma+beta
// Attn: no online max (bounded scores, scale-invariant softmax) -> raw v_exp_f32.
// NEW vs R8: wave-parity subtile STAGGER (attn s-order, gemm kk-order) to break
// the barrier-lockstep convoy (all waves hitting LDS/VALU/MFMA phases together).

#define DM 1024
#define SEQ 2048
#define NB 2
#define NH 16
#define DH 64

typedef __attribute__((ext_vector_type(8))) short bf16x8;
typedef __attribute__((ext_vector_type(4))) float f32x4;
typedef __attribute__((ext_vector_type(4))) unsigned int u32x4;

__device__ __forceinline__ float bf2f(short s) {
  unsigned u = ((unsigned)(unsigned short)s) << 16;
  return __builtin_bit_cast(float, u);
}
__device__ __forceinline__ short f2bf(float f) {
  unsigned u = __builtin_bit_cast(unsigned, f);
  u += 0x7fffu + ((u >> 16) & 1u);  // RNE
  return (short)(u >> 16);
}
__device__ __forceinline__ unsigned cvt_pk_bf16(float lo, float hi) {
  unsigned r;
  asm("v_cvt_pk_bf16_f32 %0, %1, %2" : "=v"(r) : "v"(lo), "v"(hi));
  return r;
}
__device__ __forceinline__ float exp2_fast(float x) {
  float r;
  asm("v_exp_f32 %0, %1" : "=v"(r) : "v"(x));
  return r;
}

#define GLL16(gsrc, ldst)                                                     \
  __builtin_amdgcn_global_load_lds(                                           \
      (const __attribute__((address_space(1))) void*)(gsrc),                  \
      (__attribute__((address_space(3))) void*)(ldst), 16, 0, 0)

#define WAIT_VM(N)                                                            \
  asm volatile("s_waitcnt vmcnt(" #N ")" ::: "memory");                       \
  __builtin_amdgcn_s_barrier();                                               \
  __builtin_amdgcn_sched_barrier(0)

// ---------------------------------------------------------------- transpose
__global__ __launch_bounds__(256) void k_transpose(
    const float* __restrict__ Wq, const float* __restrict__ Wk,
    const float* __restrict__ Wv, const float* __restrict__ Wo,
    short* __restrict__ Wt_all) {
  const int z = blockIdx.z;
  const float* src = (z == 0) ? Wq : (z == 1) ? Wk : (z == 2) ? Wv : Wo;
  short* dst = Wt_all + (size_t)z * (DM * DM);
  __shared__ float t[32][33];
  const int n0 = blockIdx.x * 32, k0 = blockIdx.y * 32;
  const int tx = threadIdx.x, ty = threadIdx.y;  // (32,8)
#pragma unroll
  for (int i = 0; i < 32; i += 8)
    t[ty + i][tx] = src[(size_t)(k0 + ty + i) * DM + n0 + tx];
  __syncthreads();
#pragma unroll
  for (int i = 0; i < 32; i += 8)
    dst[(size_t)(n0 + ty + i) * DM + k0 + tx] = f2bf(t[tx][ty + i]);
}

// ---------------------------------------------------------------- f32->bf16
__global__ __launch_bounds__(256) void k_cvt(const float* __restrict__ q,
                                             const float* __restrict__ kv,
                                             short* __restrict__ qb,
                                             short* __restrict__ kvb) {
  const int i = blockIdx.x * 256 + threadIdx.x;
  const int half = 524288;
  const float* src = (i < half) ? q : kv;
  short* dst = (i < half) ? qb : kvb;
  const size_t j = (size_t)((i < half) ? i : i - half) * 8;
  const float4 a = *(const float4*)(src + j);
  const float4 b = *(const float4*)(src + j + 4);
  u32x4 pw;
  pw[0] = cvt_pk_bf16(a.x, a.y);
  pw[1] = cvt_pk_bf16(a.z, a.w);
  pw[2] = cvt_pk_bf16(b.x, b.y);
  pw[3] = cvt_pk_bf16(b.z, b.w);
  *(bf16x8*)(dst + j) = __builtin_bit_cast(bf16x8, pw);
}

// ---------------------------------------------------------------- GEMM body
// C[m,n] = (sum_k A[m,k]*Wt[n,k] + bias[n]) * cscale; M=4096, N=K=1024.
// 128x128 tile, BK=64, 4 waves, 4x4 frags of 16x16x32. Single-buffer,
// 2 __syncthreads per K-step (R8-proven; 32KB LDS). kk order staggered by
// wave parity to de-synchronize LDS/MFMA phases across waves.
__device__ __forceinline__ void gemm_body64(short* As, short* Bs,
                                            const short* __restrict__ X,
                                            const short* __restrict__ Wt,
                                            const float* __restrict__ bias,
                                            short* __restrict__ out,
                                            int vt_mode, float cscale,
                                            int bx, int by) {
  const int tid = threadIdx.x;
  const int w = tid >> 6, l = tid & 63;
  const int g = l >> 4, qi = l & 15;
  const int n0 = bx * 128;
  const int m0 = by * 128;
  const int wr = w >> 1, wc = w & 1;

  f32x4 acc[4][4];
#pragma unroll
  for (int m = 0; m < 4; m++)
#pragma unroll
    for (int n = 0; n < 4; n++) acc[m][n] = (f32x4){0.f, 0.f, 0.f, 0.f};

  // staging: GLL16 j covers rows j*32 + w*8 + (l>>3); col-block (l&7)^((l>>3)&7)
  const int srow = w * 8 + (l >> 3);
  const int scol = ((l & 7) ^ ((l >> 3) & 7)) * 8;
  const short* Ag = X + (size_t)(m0 + srow) * DM + scol;
  const short* Bg = Wt + (size_t)(n0 + srow) * DM + scol;

  for (int k0 = 0; k0 < DM; k0 += 64) {
    __syncthreads();
#pragma unroll
    for (int j = 0; j < 4; j++) {
      GLL16(Ag + (size_t)(j * 32) * DM + k0, As + j * 2048 + w * 512);
      GLL16(Bg + (size_t)(j * 32) * DM + k0, Bs + j * 2048 + w * 512);
    }
    __syncthreads();

#pragma unroll
    for (int kk = 0; kk < 2; kk++) {
      const int kx = kk ^ (w & 1);  // wave-parity stagger
      bf16x8 a[4], b[4];
#pragma unroll
      for (int m = 0; m < 4; m++)
        a[m] = *(const bf16x8*)&As[(wr * 64 + m * 16 + qi) * 64 +
                                   (((kx * 4 + g) ^ (qi & 7)) * 8)];
#pragma unroll
      for (int n = 0; n < 4; n++)
        b[n] = *(const bf16x8*)&Bs[(wc * 64 + n * 16 + qi) * 64 +
                                   (((kx * 4 + g) ^ (qi & 7)) * 8)];
      __builtin_amdgcn_s_setprio(1);
#pragma unroll
      for (int m = 0; m < 4; m++)
#pragma unroll
        for (int n = 0; n < 4; n++)
          acc[m][n] = __builtin_amdgcn_mfma_f32_16x16x32_bf16(a[m], b[n],
                                                              acc[m][n], 0, 0, 0);
      __builtin_amdgcn_s_setprio(0);
    }
  }

  const int col0 = n0 + wc * 64;
  const int row0 = m0 + wr * 64;
  float bfv[4];
#pragma unroll
  for (int n = 0; n < 4; n++) bfv[n] = bias[col0 + n * 16 + qi];

  if (!vt_mode) {
#pragma unroll
    for (int m = 0; m < 4; m++) {
#pragma unroll
      for (int n = 0; n < 4; n++) {
        const int col = col0 + n * 16 + qi;
#pragma unroll
        for (int r = 0; r < 4; r++) {
          const int row = row0 + m * 16 + g * 4 + r;
          out[(size_t)row * DM + col] = f2bf((acc[m][n][r] + bfv[n]) * cscale);
        }
      }
    }
  } else {
    // V transposed per head: out[((b*NH+h)*DH+d)*SEQ + s]
#pragma unroll
    for (int m = 0; m < 4; m++) {
      const int s_base = row0 + m * 16 + g * 4;
      const int bb = s_base >> 11;
      const int s = s_base & (SEQ - 1);
#pragma unroll
      for (int n = 0; n < 4; n++) {
        const int col = col0 + n * 16 + qi;
        const int h = col >> 6, d = col & 63;
        ushort4 v;
        v.x = (unsigned short)f2bf(acc[m][n][0] + bfv[n]);
        v.y = (unsigned short)f2bf(acc[m][n][1] + bfv[n]);
        v.z = (unsigned short)f2bf(acc[m][n][2] + bfv[n]);
        v.w = (unsigned short)f2bf(acc[m][n][3] + bfv[n]);
        *(ushort4*)&out[(((size_t)bb * NH + h) * DH + d) * SEQ + s] = v;
      }
    }
  }
}

// XCD-chunked remap of the (8 x-blocks, 32 y-blocks) grid.
__device__ __forceinline__ void xcd_remap(int& bx, int& by) {
  const int lin2 = blockIdx.x + 8 * blockIdx.y;
  const int xcd = lin2 & 7, jj = lin2 >> 3;
  bx = jj & 7;
  by = xcd * 4 + (jj >> 3);
}

__global__ __launch_bounds__(256) void k_gemm_qkv(
    const short* __restrict__ qb, const short* __restrict__ kvb,
    const short* __restrict__ Wt, const float* __restrict__ bq,
    const float* __restrict__ bk, const float* __restrict__ bv,
    short* __restrict__ qm, short* __restrict__ km, short* __restrict__ vtb) {
  __shared__ short As[8192], Bs[8192];
  const int z = blockIdx.z;
  const short* X = (z == 0) ? qb : kvb;
  const short* W = Wt + (size_t)z * (DM * DM);
  const float* bias = (z == 0) ? bq : (z == 1) ? bk : bv;
  short* out = (z == 0) ? qm : (z == 1) ? km : vtb;
  const float cs = (z == 0) ? 0.18033688011112042f : 1.0f;  // log2e/8
  int bx, by;
  xcd_remap(bx, by);
  gemm_body64(As, Bs, X, W, bias, out, z == 2, cs, bx, by);
}

__global__ __launch_bounds__(256) void k_gemm_o(
    const short* __restrict__ attn, const short* __restrict__ Wto,
    const float* __restrict__ bo, short* __restrict__ om) {
  __shared__ short As[8192], Bs[8192];
  int bx, by;
  xcd_remap(bx, by);
  gemm_body64(As, Bs, attn, Wto, bo, om, 0, 1.0f, bx, by);
}

// ---------------------------------------------------------------- attention
// R8-proven: block = 8 waves x 32 q-rows (G=2 q-groups sharing K/V LDS reads)
// = 256 q-rows of one (b,h); 256 blocks (1/CU). 3 LDS buffers, depth-2
// prefetch, counted s_waitcnt vmcnt(2) + raw s_barrier per tile; last tile
// peeled at vmcnt(0). No-max softmax. NEW: s-subtile order staggered by wave
// parity (odd waves do s=1 first) to break the LDS/VALU phase convoy.
__global__ __launch_bounds__(512) void k_attn(const short* __restrict__ qm,
                                              const short* __restrict__ km,
                                              const short* __restrict__ vt,
                                              short* __restrict__ attn) {
  __shared__ short lds[3][8192];  // per buf: K [0..4095], V^T [4096..8191]

  // XCD-chunked: xcd = lin&7 gets 4 whole (b,h) pairs -> K/V L2-resident.
  const int lin = blockIdx.x;
  const int x = lin & 7, j = lin >> 3;
  const int pair = x + 8 * (j >> 3), qb = j & 7;
  const int h = pair & 15, bb = pair >> 4;
  const int q0 = qb * 256;

  const int tid = threadIdx.x;
  const int w = tid >> 6, l = tid & 63;
  const int g = l >> 4, qi = l & 15;

  const size_t bbS = (size_t)bb * SEQ;
  const size_t vbase = ((size_t)(bb * NH + h)) * DH * SEQ;
  const short* __restrict__ kmh = km + bbS * DM + h * DH;

  // staging lane constants (512 thr: row tid>>3 = 0..63, slot tid&7)
  const int skey = tid >> 3;
  const int sslot = tid & 7;
  const int kgq = sslot ^ ((skey >> 1) & 7);  // K dim-block at this slot
  const int vkb = sslot ^ (skey & 7);         // V key-block at this slot
  const short* __restrict__ srcK0 = kmh + (size_t)skey * DM + kgq * 8;
  const short* __restrict__ srcV0 = vt + vbase + (size_t)skey * SEQ + vkb * 8;

#define STAGE(buf, kk0)                                                       \
  {                                                                           \
    GLL16(srcK0 + (size_t)(kk0)*DM, &lds[buf][w * 512]);                      \
    GLL16(srcV0 + (kk0), &lds[buf][4096 + w * 512]);                          \
  }

  // Q fragments (2 q-groups: rows rowA, rowA+16), pre-scaled by log2e/8
  const int rowA = q0 + w * 32 + qi;
  const short* QpA = qm + (bbS + rowA) * DM + h * DH;
  const bf16x8 qA0 = *(const bf16x8*)(QpA + 8 * g);
  const bf16x8 qA1 = *(const bf16x8*)(QpA + 32 + 8 * g);
  const bf16x8 qB0 = *(const bf16x8*)(QpA + 16 * DM + 8 * g);
  const bf16x8 qB1 = *(const bf16x8*)(QpA + 16 * DM + 32 + 8 * g);

  float ssA[4], ssB[4];
#pragma unroll
  for (int i = 0; i < 4; i++) { ssA[i] = 0.f; ssB[i] = 0.f; }
  f32x4 oA[4], oB[4];
#pragma unroll
  for (int f = 0; f < 4; f++) {
    oA[f] = (f32x4){0.f, 0.f, 0.f, 0.f};
    oB[f] = (f32x4){0.f, 0.f, 0.f, 0.f};
  }

  const int xA = (g ^ (qi & 7)) * 8;
  const int xB = ((4 + g) ^ (qi & 7)) * 8;

  auto tile = [&](const short* Ks, const short* Vs) {
#pragma unroll
    for (int sidx = 0; sidx < 2; sidx++) {
      const int s = sidx ^ (w & 1);  // wave-parity stagger
      const int r0 = (32 * s + 2 * qi) * 64;
      const bf16x8 k00 = *(const bf16x8*)&Ks[r0 + xA];
      const bf16x8 k01 = *(const bf16x8*)&Ks[r0 + xB];
      const bf16x8 k10 = *(const bf16x8*)&Ks[r0 + 64 + xA];
      const bf16x8 k11 = *(const bf16x8*)&Ks[r0 + 64 + xB];

      f32x4 sA0 = (f32x4){0.f, 0.f, 0.f, 0.f};
      f32x4 sA1 = (f32x4){0.f, 0.f, 0.f, 0.f};
      f32x4 sB0 = (f32x4){0.f, 0.f, 0.f, 0.f};
      f32x4 sB1 = (f32x4){0.f, 0.f, 0.f, 0.f};
      __builtin_amdgcn_s_setprio(1);
      sA0 = __builtin_amdgcn_mfma_f32_16x16x32_bf16(k00, qA0, sA0, 0, 0, 0);
      sA0 = __builtin_amdgcn_mfma_f32_16x16x32_bf16(k01, qA1, sA0, 0, 0, 0);
      sA1 = __builtin_amdgcn_mfma_f32_16x16x32_bf16(k10, qA0, sA1, 0, 0, 0);
      sA1 = __builtin_amdgcn_mfma_f32_16x16x32_bf16(k11, qA1, sA1, 0, 0, 0);
      sB0 = __builtin_amdgcn_mfma_f32_16x16x32_bf16(k00, qB0, sB0, 0, 0, 0);
      sB0 = __builtin_amdgcn_mfma_f32_16x16x32_bf16(k01, qB1, sB0, 0, 0, 0);
      sB1 = __builtin_amdgcn_mfma_f32_16x16x32_bf16(k10, qB0, sB1, 0, 0, 0);
      sB1 = __builtin_amdgcn_mfma_f32_16x16x32_bf16(k11, qB1, sB1, 0, 0, 0);
      __builtin_amdgcn_s_setprio(0);

      // P = exp2(score); no max subtraction (bounded scores)
      float eA0[4], eA1[4], eB0[4], eB1[4];
#pragma unroll
      for (int r = 0; r < 4; r++) {
        eA0[r] = exp2_fast(sA0[r]);
        eA1[r] = exp2_fast(sA1[r]);
        eB0[r] = exp2_fast(sB0[r]);
        eB1[r] = exp2_fast(sB1[r]);
      }
#pragma unroll
      for (int r = 0; r < 4; r++) {
        ssA[r] += eA0[r] + eA1[r];
        ssB[r] += eB0[r] + eB1[r];
      }
      u32x4 pwA, pwB;
#pragma unroll
      for (int r = 0; r < 4; r++) {
        pwA[r] = cvt_pk_bf16(eA0[r], eA1[r]);
        pwB[r] = cvt_pk_bf16(eB0[r], eB1[r]);
      }
      const bf16x8 pbA = __builtin_bit_cast(bf16x8, pwA);
      const bf16x8 pbB = __builtin_bit_cast(bf16x8, pwB);

      const int vx = ((4 * s + g) ^ (qi & 7)) * 8;
      __builtin_amdgcn_s_setprio(1);
#pragma unroll
      for (int f = 0; f < 4; f++) {
        const bf16x8 vv = *(const bf16x8*)&Vs[(qi + 16 * f) * 64 + vx];
        oA[f] = __builtin_amdgcn_mfma_f32_16x16x32_bf16(vv, pbA, oA[f], 0, 0, 0);
        oB[f] = __builtin_amdgcn_mfma_f32_16x16x32_bf16(vv, pbB, oB[f], 0, 0, 0);
      }
      __builtin_amdgcn_s_setprio(0);
    }
  };

  STAGE(0, 0);
  STAGE(1, 64);
  int cur = 0;
  for (int t = 0; t < 31; ++t) {
    WAIT_VM(2);  // tile t's 2 loads done; t+1's stay in flight
    if (t < 30) {
      int n2 = cur + 2;
      if (n2 >= 3) n2 -= 3;
      STAGE(n2, (t + 2) * 64);
    }
    tile(&lds[cur][0], &lds[cur][4096]);
    cur = (cur + 1 == 3) ? 0 : cur + 1;
  }
  WAIT_VM(0);  // peeled last tile: only its own 2 loads outstanding
  tile(&lds[cur][0], &lds[cur][4096]);

  float sa = (ssA[0] + ssA[1]) + (ssA[2] + ssA[3]);
  sa += __shfl_xor(sa, 16);
  sa += __shfl_xor(sa, 32);
  const float invA = 1.f / sa;
  float sb = (ssB[0] + ssB[1]) + (ssB[2] + ssB[3]);
  sb += __shfl_xor(sb, 16);
  sb += __shfl_xor(sb, 32);
  const float invB = 1.f / sb;

  short* OpA = attn + (bbS + rowA) * DM + h * DH;
#pragma unroll
  for (int f = 0; f < 4; f++) {
    ushort4 v;
    v.x = (unsigned short)f2bf(oA[f][0] * invA);
    v.y = (unsigned short)f2bf(oA[f][1] * invA);
    v.z = (unsigned short)f2bf(oA[f][2] * invA);
    v.w = (unsigned short)f2bf(oA[f][3] * invA);
    *(ushort4*)(OpA + f * 16 + g * 4) = v;
    ushort4 u;
    u.x = (unsigned short)f2bf(oB[f][0] * invB);
    u.y = (unsigned short)f2bf(oB[f][1] * invB);
    u.z = (unsigned short)f2bf(oB[f][2] * invB);
    u.w = (unsigned short)f2bf(oB[f][3] * invB);
    *(ushort4*)(OpA + 16 * DM + f * 16 + g * 4) = u;
  }
#undef STAGE
}

// ---------------------------------------------------------------- layernorm
__global__ __launch_bounds__(256) void k_ln(const float* __restrict__ q,
                                            const short* __restrict__ om,
                                            const float* __restrict__ gamma,
                                            const float* __restrict__ beta,
                                            float* __restrict__ out) {
  const int row = blockIdx.x;
  const int t = threadIdx.x;
  const int w = t >> 6, l = t & 63;
  const size_t base = (size_t)row * DM + t * 4;
  const float4 qv = *(const float4*)(q + base);
  const ushort4 ov = *(const ushort4*)(om + base);
  float v[4];
  v[0] = qv.x + bf2f((short)ov.x);
  v[1] = qv.y + bf2f((short)ov.y);
  v[2] = qv.z + bf2f((short)ov.z);
  v[3] = qv.w + bf2f((short)ov.w);
  float s = v[0] + v[1] + v[2] + v[3];
  float s2 = v[0] * v[0] + v[1] * v[1] + v[2] * v[2] + v[3] * v[3];
#pragma unroll
  for (int off = 32; off >= 1; off >>= 1) {
    s += __shfl_xor(s, off);
    s2 += __shfl_xor(s2, off);
  }
  __shared__ float ps[4], ps2[4];
  if (l == 0) {
    ps[w] = s;
    ps2[w] = s2;
  }
  __syncthreads();
  const float St = ps[0] + ps[1] + ps[2] + ps[3];
  const float S2t = ps2[0] + ps2[1] + ps2[2] + ps2[3];
  const float mu = St * (1.f / 1024.f);
  float var = S2t * (1.f / 1024.f) - mu * mu;
  const float rstd = rsqrtf(var + 1e-5f);
  const float4 gv = *(const float4*)(gamma + t * 4);
  const float4 bv = *(const float4*)(beta + t * 4);
  float4 ovv;
  ovv.x = (v[0] - mu) * rstd * gv.x + bv.x;
  ovv.y = (v[1] - mu) * rstd * gv.y + bv.y;
  ovv.z = (v[2] - mu) * rstd * gv.z + bv.z;
  ovv.w = (v[3] - mu) * rstd * gv.w + bv.w;
  *(float4*)(out + base) = ovv;
}

// ---------------------------------------------------------------- launch
extern "C" void kernel_launch(void* const* d_in, const int* in_sizes, int n_in,
                              void* d_out, int out_size, void* d_ws, size_t ws_size,
                              hipStream_t stream) {
  const float* q = (const float*)d_in[0];
  const float* kv = (const float*)d_in[1];
  const float* Wq = (const float*)d_in[2];
  const float* bq = (const float*)d_in[3];
  const float* Wk = (const float*)d_in[4];
  const float* bk = (const float*)d_in[5];
  const float* Wv = (const float*)d_in[6];
  const float* bv = (const float*)d_in[7];
  const float* Wo = (const float*)d_in[8];
  const float* bo = (const float*)d_in[9];
  const float* gamma = (const float*)d_in[10];
  const float* beta = (const float*)d_in[11];

  short* ws = (short*)d_ws;
  short* Wt = ws;                        // 4 * 1Mi shorts (Wq^T,Wk^T,Wv^T,Wo^T)
  short* qb16 = ws + 4u * 1048576u;      // bf16(q); later attn out
  short* kvb16 = qb16 + 4194304u;        // bf16(kv); later om
  short* qm = kvb16 + 4194304u;          // [4096,1024] bf16 (pre-scaled)
  short* km = qm + 4194304u;             // [4096,1024] bf16
  short* vtb = km + 4194304u;            // [B,H,64,S] bf16
  short* attnb = qb16;
  short* om = kvb16;

  hipLaunchKernelGGL(k_transpose, dim3(32, 32, 4), dim3(32, 8), 0, stream,
                     Wq, Wk, Wv, Wo, Wt);
  hipLaunchKernelGGL(k_cvt, dim3(4096), dim3(256), 0, stream, q, kv, qb16, kvb16);
  hipLaunchKernelGGL(k_gemm_qkv, dim3(8, 32, 3), dim3(256), 0, stream,
                     qb16, kvb16, Wt, bq, bk, bv, qm, km, vtb);
  hipLaunchKernelGGL(k_attn, dim3(256), dim3(512), 0, stream,
                     qm, km, vtb, attnb);
  hipLaunchKernelGGL(k_gemm_o, dim3(8, 32, 1), dim3(256), 0, stream,
                     attnb, Wt + 3u * 1048576u, bo, om);
  hipLaunchKernelGGL(k_ln, dim3(4096), dim3(256), 0, stream,
                     q, om, gamma, beta, (float*)d_out);
}